// Round 6
// baseline (900.271 us; speedup 1.0000x reference)
//
#include <hip/hip_runtime.h>

// Problem constants (fixed by the reference)
constexpr int B = 32, S = 2048, D = 1024, N = 256;
constexpr int NCHUNK = 32;     // S/64 chunks
constexpr int SBLK   = 16;     // scan blocks (first), wave 0 only, 2 batches/wave
constexpr int WBLK   = 128;    // worker blocks: 16 waves x 1 row/wave
// Grid = 144 blocks x 1024 thr: all resident. Deadlock-free: workers' mean
// phase waits on nothing -> uflag advances -> scan advances -> sflag
// advances -> out phase advances.

#define DEV __device__ __forceinline__

// ---- DPP wave-64 reduction helpers -------------------------------------
template <int CTRL>
DEV float dpp_add(float x) {
  int y = __builtin_amdgcn_update_dpp(0, __float_as_int(x), CTRL, 0xF, 0xF, true);
  return x + __int_as_float(y);
}

DEV float rdlane(float v, int l) {
  return __int_as_float(__builtin_amdgcn_readlane(__float_as_int(v), l));
}

DEV void wave_reduce3(float& a, float& b, float& c) {
  a = dpp_add<0x111>(a); b = dpp_add<0x111>(b); c = dpp_add<0x111>(c);
  a = dpp_add<0x112>(a); b = dpp_add<0x112>(b); c = dpp_add<0x112>(c);
  a = dpp_add<0x114>(a); b = dpp_add<0x114>(b); c = dpp_add<0x114>(c);
  a = dpp_add<0x118>(a); b = dpp_add<0x118>(b); c = dpp_add<0x118>(c);
  a = dpp_add<0x142>(a); b = dpp_add<0x142>(b); c = dpp_add<0x142>(c);
  a = dpp_add<0x143>(a); b = dpp_add<0x143>(b); c = dpp_add<0x143>(c);
  a = rdlane(a, 63);
  b = rdlane(b, 63);
  c = rdlane(c, 63);
}

// Six independent sums interleaved through the DPP stages: the two batches'
// reduction chains hide each other's DPP latency.
DEV void wave_reduce6(float& a, float& b, float& c, float& d, float& e,
                      float& f) {
  a = dpp_add<0x111>(a); b = dpp_add<0x111>(b); c = dpp_add<0x111>(c);
  d = dpp_add<0x111>(d); e = dpp_add<0x111>(e); f = dpp_add<0x111>(f);
  a = dpp_add<0x112>(a); b = dpp_add<0x112>(b); c = dpp_add<0x112>(c);
  d = dpp_add<0x112>(d); e = dpp_add<0x112>(e); f = dpp_add<0x112>(f);
  a = dpp_add<0x114>(a); b = dpp_add<0x114>(b); c = dpp_add<0x114>(c);
  d = dpp_add<0x114>(d); e = dpp_add<0x114>(e); f = dpp_add<0x114>(f);
  a = dpp_add<0x118>(a); b = dpp_add<0x118>(b); c = dpp_add<0x118>(c);
  d = dpp_add<0x118>(d); e = dpp_add<0x118>(e); f = dpp_add<0x118>(f);
  a = dpp_add<0x142>(a); b = dpp_add<0x142>(b); c = dpp_add<0x142>(c);
  d = dpp_add<0x142>(d); e = dpp_add<0x142>(e); f = dpp_add<0x142>(f);
  a = dpp_add<0x143>(a); b = dpp_add<0x143>(b); c = dpp_add<0x143>(c);
  d = dpp_add<0x143>(d); e = dpp_add<0x143>(e); f = dpp_add<0x143>(f);
  a = rdlane(a, 63); b = rdlane(b, 63); c = rdlane(c, 63);
  d = rdlane(d, 63); e = rdlane(e, 63); f = rdlane(f, 63);
}

// ---- cross-block communication primitives (round-3/4/5 verified) --------
DEV float ld_agent(const float* p) {
  return __hip_atomic_load(p, __ATOMIC_RELAXED, __HIP_MEMORY_SCOPE_AGENT);
}
DEV int ld_flag(const int* p) {
  return __hip_atomic_load(p, __ATOMIC_RELAXED, __HIP_MEMORY_SCOPE_AGENT);
}

// ---- single fused kernel: mean -> scan(2 batches/wave) -> out -----------
__global__ __launch_bounds__(1024) void fused(
    const float4* __restrict__ x4, const float* __restrict__ llr,
    const float* __restrict__ logb, const float* __restrict__ c,
    const float* __restrict__ lstep, const float* __restrict__ gma,
    const float* __restrict__ bta, const float* __restrict__ logd,
    const float* __restrict__ alpha, float* __restrict__ u,
    float* __restrict__ s, int* __restrict__ uflag, int* __restrict__ sflag,
    float4* __restrict__ o4) {
  const int wv   = threadIdx.x >> 6;
  const int lane = threadIdx.x & 63;

  if (blockIdx.x >= SBLK) {
    // =================== WORKER (identical to verified round-5) ==========
    const int wb = blockIdx.x - SBLK;            // 0..127
    const int b  = wb >> 2;                      // 4 blocks per batch
    const int i  = ((wb & 3) << 4) | wv;         // row-in-chunk 0..63

    // ---- phase 1: mean (wait-free; quarter-granularity signaling) ----
    for (int ch = 0; ch < NCHUNK; ++ch) {
      const int t = (ch << 6) | i;
      const float4* xr = x4 + (size_t)(b * S + t) * (D / 4);
      float sm = 0.f;
#pragma unroll
      for (int k = 0; k < 4; ++k) {
        float4 v = xr[lane + (k << 6)];
        sm += (v.x + v.y) + (v.z + v.w);
      }
#pragma unroll
      for (int off = 32; off; off >>= 1) sm += __shfl_xor(sm, off, 64);
      if (lane == 0) atomicExch(&u[b * S + t], sm * (1.f / 1024.f));
      if ((ch & 7) == 7) {                       // quarter boundary
        asm volatile("s_waitcnt vmcnt(0)" ::: "memory");
        __syncthreads();
        if (threadIdx.x == 0) atomicAdd(&uflag[(b << 5) + (ch >> 3)], 1);
      }
    }

    // ---- phase 2: out, trailing the scan chunk-by-chunk ----
    const float asig = 1.f / (1.f + expf(-alpha[0]));
    const float dd   = expf(logd[0]);
    const float cx   = asig + (1.f - asig) * dd;
    const float cs   = 1.f - asig;
    for (int ch = 0; ch < NCHUNK; ++ch) {
      if (threadIdx.x == 0) {                    // ONE scalar poller per block
        while (ld_flag(&sflag[b << 5]) < ch + 1) __builtin_amdgcn_s_sleep(8);
      }
      __syncthreads();
      const int t = (ch << 6) | i;
      const float sv = cs * ld_agent(&s[b * S + t]);
      const float4* xr   = x4 + (size_t)(b * S + t) * (D / 4);
      float4*       orow = o4 + (size_t)(b * S + t) * (D / 4);
#pragma unroll
      for (int k = 0; k < 4; ++k) {
        float4 v = xr[lane + (k << 6)];
        float4 o;
        o.x = fmaf(cx, v.x, sv);
        o.y = fmaf(cx, v.y, sv);
        o.z = fmaf(cx, v.z, sv);
        o.w = fmaf(cx, v.w, sv);
        orow[lane + (k << 6)] = o;
      }
    }
  } else if (wv == 0) {
    // ========== SCAN: TWO batches per wave, interleaved chains ===========
    // Per-batch math is bit-identical to the verified single-batch version;
    // the second chain fills the first chain's dependency-stall slots.
    const int b0 = blockIdx.x << 1;              // batches b0, b0+1
    __builtin_amdgcn_s_setprio(1);
    const float stp = expf(lstep[0]);

    float ag[4], ab[4], bd[4], cg[4];            // batch-independent params
    float Gp = 0.f, BCp = 0.f, d0 = 0.f;
#pragma unroll
    for (int k = 0; k < 4; ++k) {
      const int n = (k << 6) | lane;
      const float lam = -expf(llr[n]);
      const float sl  = stp * lam;
      const float adisc = (2.f + sl) / (2.f - sl);
      const float bdisc = stp * (1.f + adisc) * expf(logb[n]) * 0.5f;
      const float g  = gma[n];
      const float be = bta[n];
      const float cc = c[n];
      ag[k] = adisc * g;
      ab[k] = adisc * be;
      bd[k] = bdisc;
      cg[k] = cc * g;
      Gp  += cg[k];
      BCp += cc * be;
    }
    wave_reduce3(Gp, BCp, d0);
    const float G = Gp, BC = BCp;
    const float Ceps = 65536.f * 1e-5f;

    const float* urowA = u + b0 * S;
    const float* urowB = u + (b0 + 1) * S;
    float* srowA = s + b0 * S;
    float* srowB = s + (b0 + 1) * S;

    // wait for quarter 0 of u for BOTH batches (workers run far ahead)
    while (ld_flag(&uflag[b0 << 5]) < 4 ||
           ld_flag(&uflag[(b0 + 1) << 5]) < 4)
      __builtin_amdgcn_s_sleep(2);
    __threadfence();
    float uchA = ld_agent(urowA + lane);
    float uchB = ld_agent(urowB + lane);
    const float u0A = rdlane(uchA, 0);
    const float u0B = rdlane(uchB, 0);
    float zA0 = bd[0] * u0A, zA1 = bd[1] * u0A, zA2 = bd[2] * u0A,
          zA3 = bd[3] * u0A;
    float zB0 = bd[0] * u0B, zB1 = bd[1] * u0B, zB2 = bd[2] * u0B,
          zB3 = bd[3] * u0B;

    for (int chn = 0; chn < NCHUNK; ++chn) {
      float uchA_next = uchA, uchB_next = uchB;  // chunk 31: feeds dead state
      if (chn < NCHUNK - 1) {
        if (((chn + 1) & 7) == 0) {              // next quarter boundary
          const int q = (chn + 1) >> 3;
          while (ld_flag(&uflag[(b0 << 5) + q]) < 4 ||
                 ld_flag(&uflag[((b0 + 1) << 5) + q]) < 4)
            __builtin_amdgcn_s_sleep(2);
          __threadfence();
        }
        uchA_next = ld_agent(urowA + ((chn + 1) << 6) + lane);
        uchB_next = ld_agent(urowB + ((chn + 1) << 6) + lane);
      }
      float stkA = 0.f, stkB = 0.f;
#pragma unroll 8
      for (int tt = 0; tt < 64; ++tt) {
        float s1A = (zA0 + zA1) + (zA2 + zA3);
        float s2A = fmaf(zA0, zA0, zA1 * zA1) + fmaf(zA2, zA2, zA3 * zA3);
        float s3A = fmaf(zA0, cg[0], zA1 * cg[1]) + fmaf(zA2, cg[2], zA3 * cg[3]);
        float s1B = (zB0 + zB1) + (zB2 + zB3);
        float s2B = fmaf(zB0, zB0, zB1 * zB1) + fmaf(zB2, zB2, zB3 * zB3);
        float s3B = fmaf(zB0, cg[0], zB1 * cg[1]) + fmaf(zB2, cg[2], zB3 * cg[3]);
        wave_reduce6(s1A, s2A, s3A, s1B, s2B, s3B);
        const float qA = fmaf(256.f, s2A, fmaf(-s1A, s1A, Ceps));
        const float qB = fmaf(256.f, s2B, fmaf(-s1B, s1B, Ceps));
        const float rA = __builtin_amdgcn_rsqf(qA);   // v_rsq_f32
        const float rB = __builtin_amdgcn_rsqf(qB);
        const float stA = fmaf(rA, fmaf(256.f, s3A, -s1A * G), BC);
        const float stB = fmaf(rB, fmaf(256.f, s3B, -s1B * G), BC);
        stkA = (lane == tt) ? stA : stkA;
        stkB = (lane == tt) ? stB : stkB;

        float unA, unB;                          // uniform branch, cheap
        if (tt != 63) {
          unA = rdlane(uchA, tt + 1);            // runtime-uniform readlane
          unB = rdlane(uchB, tt + 1);
        } else {
          unA = rdlane(uchA_next, 0);
          unB = rdlane(uchB_next, 0);
        }
        const float wA0 = fmaf(256.f, zA0, -s1A);
        const float wA1 = fmaf(256.f, zA1, -s1A);
        const float wA2 = fmaf(256.f, zA2, -s1A);
        const float wA3 = fmaf(256.f, zA3, -s1A);
        const float wB0 = fmaf(256.f, zB0, -s1B);
        const float wB1 = fmaf(256.f, zB1, -s1B);
        const float wB2 = fmaf(256.f, zB2, -s1B);
        const float wB3 = fmaf(256.f, zB3, -s1B);
        zA0 = fmaf(ag[0] * wA0, rA, fmaf(bd[0], unA, ab[0]));
        zA1 = fmaf(ag[1] * wA1, rA, fmaf(bd[1], unA, ab[1]));
        zA2 = fmaf(ag[2] * wA2, rA, fmaf(bd[2], unA, ab[2]));
        zA3 = fmaf(ag[3] * wA3, rA, fmaf(bd[3], unA, ab[3]));
        zB0 = fmaf(ag[0] * wB0, rB, fmaf(bd[0], unB, ab[0]));
        zB1 = fmaf(ag[1] * wB1, rB, fmaf(bd[1], unB, ab[1]));
        zB2 = fmaf(ag[2] * wB2, rB, fmaf(bd[2], unB, ab[2]));
        zB3 = fmaf(ag[3] * wB3, rB, fmaf(bd[3], unB, ab[3]));
      }
      // Deferred publish: drain retires chunk chn-1's exchs (issued 64 steps
      // ago -> instant), flag chn-1 ready, then issue chunk chn's exchs.
      asm volatile("s_waitcnt vmcnt(0)" ::: "memory");
      if (lane < 2) atomicExch(&sflag[(b0 + lane) << 5], chn);
      atomicExch(&srowA[(chn << 6) + lane], stkA);
      atomicExch(&srowB[(chn << 6) + lane], stkB);
      uchA = uchA_next;
      uchB = uchB_next;
    }
    asm volatile("s_waitcnt vmcnt(0)" ::: "memory");    // retire chunk 31
    if (lane < 2) atomicExch(&sflag[(b0 + lane) << 5], NCHUNK);
  }
}

extern "C" void kernel_launch(void* const* d_in, const int* in_sizes, int n_in,
                              void* d_out, int out_size, void* d_ws, size_t ws_size,
                              hipStream_t stream) {
  const float* x     = (const float*)d_in[0];
  const float* llr   = (const float*)d_in[1];
  const float* logb  = (const float*)d_in[2];
  const float* c     = (const float*)d_in[3];
  const float* logd  = (const float*)d_in[4];
  const float* lstep = (const float*)d_in[5];
  const float* alpha = (const float*)d_in[6];
  const float* gma   = (const float*)d_in[7];
  const float* bta   = (const float*)d_in[8];

  float* u     = (float*)d_ws;            // B*S floats
  float* s     = u + B * S;               // B*S floats
  int*   uflag = (int*)(s + B * S);       // B*32 ints: one 128B line per batch
  int*   sflag = uflag + B * 32;          // B*32 ints: one 128B line per batch

  hipMemsetAsync(uflag, 0, 2 * B * 32 * sizeof(int), stream);
  fused<<<SBLK + WBLK, 1024, 0, stream>>>(
      (const float4*)x, llr, logb, c, lstep, gma, bta, logd, alpha,
      u, s, uflag, sflag, (float4*)d_out);
}

// Round 7
// 765.102 us; speedup vs baseline: 1.1767x; 1.1767x over previous
//
#include <hip/hip_runtime.h>

// Problem constants (fixed by the reference)
constexpr int B = 32, S = 2048, D = 1024, N = 256;
constexpr int NCHUNK = 32;     // S/64 chunks
constexpr int SBLK   = 32;     // scan blocks (first), wave 0 only, 1 batch/wave
constexpr int WBLK   = 128;    // worker blocks: 16 waves x 1 row/wave
// Grid = 160 blocks x 1024 thr, launch_bounds(1024,4) -> 1 block/CU: every
// block owns its CU (scan waves get private issue bandwidth). Deadlock-free:
// workers' mean phase waits on nothing -> uflag advances -> scan advances ->
// sflag advances -> out phase advances.

#define DEV __device__ __forceinline__

// ---- DPP wave-64 reduction helpers -------------------------------------
template <int CTRL>
DEV float dpp_add(float x) {
  int y = __builtin_amdgcn_update_dpp(0, __float_as_int(x), CTRL, 0xF, 0xF, true);
  return x + __int_as_float(y);
}

DEV float rdlane(float v, int l) {
  return __int_as_float(__builtin_amdgcn_readlane(__float_as_int(v), l));
}

DEV void wave_reduce3(float& a, float& b, float& c) {
  a = dpp_add<0x111>(a); b = dpp_add<0x111>(b); c = dpp_add<0x111>(c);
  a = dpp_add<0x112>(a); b = dpp_add<0x112>(b); c = dpp_add<0x112>(c);
  a = dpp_add<0x114>(a); b = dpp_add<0x114>(b); c = dpp_add<0x114>(c);
  a = dpp_add<0x118>(a); b = dpp_add<0x118>(b); c = dpp_add<0x118>(c);
  a = dpp_add<0x142>(a); b = dpp_add<0x142>(b); c = dpp_add<0x142>(c);
  a = dpp_add<0x143>(a); b = dpp_add<0x143>(b); c = dpp_add<0x143>(c);
  a = rdlane(a, 63);
  b = rdlane(b, 63);
  c = rdlane(c, 63);
}

// Four independent sums interleaved through the DPP stages.
DEV void wave_reduce4(float& a, float& b, float& c, float& d) {
  a = dpp_add<0x111>(a); b = dpp_add<0x111>(b); c = dpp_add<0x111>(c); d = dpp_add<0x111>(d);
  a = dpp_add<0x112>(a); b = dpp_add<0x112>(b); c = dpp_add<0x112>(c); d = dpp_add<0x112>(d);
  a = dpp_add<0x114>(a); b = dpp_add<0x114>(b); c = dpp_add<0x114>(c); d = dpp_add<0x114>(d);
  a = dpp_add<0x118>(a); b = dpp_add<0x118>(b); c = dpp_add<0x118>(c); d = dpp_add<0x118>(d);
  a = dpp_add<0x142>(a); b = dpp_add<0x142>(b); c = dpp_add<0x142>(c); d = dpp_add<0x142>(d);
  a = dpp_add<0x143>(a); b = dpp_add<0x143>(b); c = dpp_add<0x143>(c); d = dpp_add<0x143>(d);
  a = rdlane(a, 63); b = rdlane(b, 63); c = rdlane(c, 63); d = rdlane(d, 63);
}

// ---- cross-block communication primitives (round-3/4/5 verified) --------
DEV float ld_agent(const float* p) {
  return __hip_atomic_load(p, __ATOMIC_RELAXED, __HIP_MEMORY_SCOPE_AGENT);
}
DEV int ld_flag(const int* p) {
  return __hip_atomic_load(p, __ATOMIC_RELAXED, __HIP_MEMORY_SCOPE_AGENT);
}

// ---- single fused kernel: mean -> scan(decoupled reduce) -> out ---------
__global__ __launch_bounds__(1024, 4) void fused(
    const float4* __restrict__ x4, const float* __restrict__ llr,
    const float* __restrict__ logb, const float* __restrict__ c,
    const float* __restrict__ lstep, const float* __restrict__ gma,
    const float* __restrict__ bta, const float* __restrict__ logd,
    const float* __restrict__ alpha, float* __restrict__ u,
    float* __restrict__ s, int* __restrict__ uflag, int* __restrict__ sflag,
    float4* __restrict__ o4) {
  const int wv   = threadIdx.x >> 6;
  const int lane = threadIdx.x & 63;

  if (blockIdx.x >= SBLK) {
    // =================== WORKER (identical to verified round-5) ==========
    const int wb = blockIdx.x - SBLK;            // 0..127
    const int b  = wb >> 2;                      // 4 blocks per batch
    const int i  = ((wb & 3) << 4) | wv;         // row-in-chunk 0..63

    // ---- phase 1: mean (wait-free; quarter-granularity signaling) ----
    for (int ch = 0; ch < NCHUNK; ++ch) {
      const int t = (ch << 6) | i;
      const float4* xr = x4 + (size_t)(b * S + t) * (D / 4);
      float sm = 0.f;
#pragma unroll
      for (int k = 0; k < 4; ++k) {
        float4 v = xr[lane + (k << 6)];
        sm += (v.x + v.y) + (v.z + v.w);
      }
#pragma unroll
      for (int off = 32; off; off >>= 1) sm += __shfl_xor(sm, off, 64);
      if (lane == 0) atomicExch(&u[b * S + t], sm * (1.f / 1024.f));
      if ((ch & 7) == 7) {                       // quarter boundary
        asm volatile("s_waitcnt vmcnt(0)" ::: "memory");
        __syncthreads();
        if (threadIdx.x == 0) atomicAdd(&uflag[(b << 5) + (ch >> 3)], 1);
      }
    }

    // ---- phase 2: out, trailing the scan chunk-by-chunk ----
    const float asig = 1.f / (1.f + expf(-alpha[0]));
    const float dd   = expf(logd[0]);
    const float cx   = asig + (1.f - asig) * dd;
    const float cs   = 1.f - asig;
    for (int ch = 0; ch < NCHUNK; ++ch) {
      if (threadIdx.x == 0) {                    // ONE scalar poller per block
        while (ld_flag(&sflag[b << 5]) < ch + 1) __builtin_amdgcn_s_sleep(8);
      }
      __syncthreads();
      const int t = (ch << 6) | i;
      const float sv = cs * ld_agent(&s[b * S + t]);
      const float4* xr   = x4 + (size_t)(b * S + t) * (D / 4);
      float4*       orow = o4 + (size_t)(b * S + t) * (D / 4);
#pragma unroll
      for (int k = 0; k < 4; ++k) {
        float4 v = xr[lane + (k << 6)];
        float4 o;
        o.x = fmaf(cx, v.x, sv);
        o.y = fmaf(cx, v.y, sv);
        o.z = fmaf(cx, v.z, sv);
        o.w = fmaf(cx, v.w, sv);
        orow[lane + (k << 6)] = o;
      }
    }
  } else if (wv == 0) {
    // ===== SCAN, decoupled reductions ====================================
    // z-trajectory is bit-identical to the verified version:
    //   z' = fma(ag*w, r, fma(bd,u,ab)),  w = 256z - s1.
    // s1,s2,s3 come from a scalar recurrence over reductions of v = ag*w and
    // k = bd*u+ab, which do NOT depend on r -> the 6-stage DPP reduce runs in
    // parallel with rsq and spans two steps instead of sitting in every step.
    const int b = blockIdx.x;                    // batch 0..31, private CU
    __builtin_amdgcn_s_setprio(1);
    const float stp = expf(lstep[0]);

    float ag[4], ab[4], bd[4], cg[4];
    float Gp = 0.f, BCp = 0.f, SBDp = 0.f;
    float SABp = 0.f, SBD2p = 0.f, SBDABp = 0.f;
    float SAB2p = 0.f, SCBDp = 0.f, SCABp = 0.f;
#pragma unroll
    for (int k = 0; k < 4; ++k) {
      const int n = (k << 6) | lane;
      const float lam = -expf(llr[n]);
      const float sl  = stp * lam;
      const float adisc = (2.f + sl) / (2.f - sl);
      const float bdisc = stp * (1.f + adisc) * expf(logb[n]) * 0.5f;
      const float g  = gma[n];
      const float be = bta[n];
      const float cc = c[n];
      ag[k] = adisc * g;
      ab[k] = adisc * be;
      bd[k] = bdisc;
      cg[k] = cc * g;
      Gp    += cg[k];
      BCp   += cc * be;
      SBDp  += bd[k];
      SABp  += ab[k];
      SBD2p += bd[k] * bd[k];
      SBDABp+= bd[k] * ab[k];
      SAB2p += ab[k] * ab[k];
      SCBDp += cg[k] * bd[k];
      SCABp += cg[k] * ab[k];
    }
    wave_reduce3(Gp, BCp, SBDp);
    wave_reduce3(SABp, SBD2p, SBDABp);
    wave_reduce3(SAB2p, SCBDp, SCABp);
    const float G = Gp, BC = BCp;
    const float SBD = SBDp, SAB = SABp, SBD2 = SBD2p;
    const float SBDAB = SBDABp, SAB2 = SAB2p, SCBD = SCBDp, SCAB = SCABp;
    const float Ceps = 65536.f * 1e-5f;

    const float* urow = u + b * S;
    float* srow = s + b * S;

    // wait for quarter 0 of u (the only real wait, ~13us)
    while (ld_flag(&uflag[b << 5]) < 4) __builtin_amdgcn_s_sleep(2);
    __threadfence();
    float uch = ld_agent(urow + lane);           // chunk 0 of u (bypass)
    const float u0 = rdlane(uch, 0);
    float z0 = bd[0] * u0, z1 = bd[1] * u0, z2 = bd[2] * u0, z3 = bd[3] * u0;
    // initial sums of z = bd*u0 (exact scalar precomputes)
    float s1 = u0 * SBD;
    float s2 = u0 * u0 * SBD2;
    float s3 = u0 * SCBD;

    for (int chn = 0; chn < NCHUNK; ++chn) {
      float uch_next = uch;             // chunk 31: value only feeds dead state
      if (chn < NCHUNK - 1) {
        if (((chn + 1) & 7) == 0) {     // next quarter (workers far ahead)
          while (ld_flag(&uflag[(b << 5) + ((chn + 1) >> 3)]) < 4)
            __builtin_amdgcn_s_sleep(2);
          __threadfence();
        }
        uch_next = ld_agent(urow + ((chn + 1) << 6) + lane);  // prefetch
      }
      float stk = 0.f;
#pragma unroll 16
      for (int tt = 0; tt < 64; ++tt) {
        // scalar head: r and the readout from the recurrence-held sums
        const float q  = fmaf(256.f, s2, fmaf(-s1, s1, Ceps));
        const float r  = __builtin_amdgcn_rsqf(q);        // v_rsq_f32
        const float st = fmaf(r, fmaf(256.f, s3, -s1 * G), BC);
        stk = (lane == tt) ? st : stk;

        float un;
        if (tt != 63) un = rdlane(uch, tt + 1);           // uniform index
        else          un = rdlane(uch_next, 0);

        // v, k: independent of r (only s1 from two fmas back)
        const float w0 = fmaf(256.f, z0, -s1);
        const float w1 = fmaf(256.f, z1, -s1);
        const float w2 = fmaf(256.f, z2, -s1);
        const float w3 = fmaf(256.f, z3, -s1);
        const float v0 = ag[0] * w0, v1 = ag[1] * w1;
        const float v2 = ag[2] * w2, v3 = ag[3] * w3;
        const float k0 = fmaf(bd[0], un, ab[0]);
        const float k1 = fmaf(bd[1], un, ab[1]);
        const float k2 = fmaf(bd[2], un, ab[2]);
        const float k3 = fmaf(bd[3], un, ab[3]);
        // state update (bit-identical to verified baseline)
        z0 = fmaf(v0, r, k0);
        z1 = fmaf(v1, r, k1);
        z2 = fmaf(v2, r, k2);
        z3 = fmaf(v3, r, k3);
        // v-monomial reductions: do NOT wait on r; overlap rsq & next head
        float P1 = (v0 + v1) + (v2 + v3);
        float P2 = fmaf(v0, v0, v1 * v1) + fmaf(v2, v2, v3 * v3);
        float P3 = fmaf(v0, k0, v1 * k1) + fmaf(v2, k2, v3 * k3);
        float P6 = fmaf(v0, cg[0], v1 * cg[1]) + fmaf(v2, cg[2], v3 * cg[3]);
        wave_reduce4(P1, P2, P3, P6);
        // scalar recurrence: sums of z' = r*v + k
        const float Sk1 = fmaf(un, SBD, SAB);
        const float Sk2 = fmaf(un, fmaf(un, SBD2, 2.f * SBDAB), SAB2);
        const float Sck = fmaf(un, SCBD, SCAB);
        s1 = fmaf(r, P1, Sk1);
        s2 = fmaf(r, fmaf(r, P2, 2.f * P3), Sk2);
        s3 = fmaf(r, P6, Sck);
      }
      // Deferred publish: drain retires chunk chn-1's exch (issued 64 steps
      // ago -> instant), flag chn-1 ready, then issue chunk chn's exch.
      asm volatile("s_waitcnt vmcnt(0)" ::: "memory");
      if (lane == 0) atomicExch(&sflag[b << 5], chn);   // chunks < chn ready
      atomicExch(&srow[(chn << 6) + lane], stk);        // publish s chunk chn
      uch = uch_next;
    }
    asm volatile("s_waitcnt vmcnt(0)" ::: "memory");    // retire chunk 31
    if (lane == 0) atomicExch(&sflag[b << 5], NCHUNK);  // all chunks ready
  }
}

extern "C" void kernel_launch(void* const* d_in, const int* in_sizes, int n_in,
                              void* d_out, int out_size, void* d_ws, size_t ws_size,
                              hipStream_t stream) {
  const float* x     = (const float*)d_in[0];
  const float* llr   = (const float*)d_in[1];
  const float* logb  = (const float*)d_in[2];
  const float* c     = (const float*)d_in[3];
  const float* logd  = (const float*)d_in[4];
  const float* lstep = (const float*)d_in[5];
  const float* alpha = (const float*)d_in[6];
  const float* gma   = (const float*)d_in[7];
  const float* bta   = (const float*)d_in[8];

  float* u     = (float*)d_ws;            // B*S floats
  float* s     = u + B * S;               // B*S floats
  int*   uflag = (int*)(s + B * S);       // B*32 ints: one 128B line per batch
  int*   sflag = uflag + B * 32;          // B*32 ints: one 128B line per batch

  hipMemsetAsync(uflag, 0, 2 * B * 32 * sizeof(int), stream);
  fused<<<SBLK + WBLK, 1024, 0, stream>>>(
      (const float4*)x, llr, logb, c, lstep, gma, bta, logd, alpha,
      u, s, uflag, sflag, (float4*)d_out);
}